// Round 17
// baseline (178.153 us; speedup 1.0000x reference)
//
#include <hip/hip_runtime.h>
#include <hip/hip_bf16.h>
#include <stdint.h>

// ---------------------------------------------------------------------------
// TensorNet: fused encoder MLP (128->256->256->256, relu) over 32x4096 tokens,
// per-batch mean -> p = relu(m^2) -> decoder MLP (256->512->512->10).
// Inputs/outputs fp32. Encoder via bf16 MFMA (A=weights M=hidden, B=act
// N=tokens) + fp32 accum. 3 launch nodes (dependency floor; coop dead R11).
// R17: MTILE 64 -> 128 tokens (512 thr, 8 waves; wave owns 32 hidden cols,
// acc[2][8] = same 64 VGPRs). LDS 33.8 -> 67.6 KB (2 blocks/CU, still
// 16 waves/CU); HALF the barrier drains per unit work — the m93 ladder's
// tile-size step (64->128 = 1.51x in the verified GEMM ladder).
// Rejected in prior rounds: launch_bounds min-waves (spills R5), direct-x
// layer1 + shfl reduce (R5/6), a-frag ping-pong (R13), coop (R11),
// decoder-tail fusion (R14/15), __threadfence in hot path (R14).
// ---------------------------------------------------------------------------

#define NIN   128
#define NHID  256
#define NDEC  512
#define NOUTC 10
#define BATCH 32
#define NTOK  4096
#define MTILE 128
#define TPB   (NTOK / MTILE)             // 32 encoder blocks per batch
#define NBLK  (BATCH * TPB)              // 1024 encoder tiles
#define XPAD  136                         // x-tile LDS row stride (bf16)
#define HPAD  264                         // h-tile LDS row stride (bf16)

typedef short bf16x8 __attribute__((ext_vector_type(8)));
typedef float floatx4 __attribute__((ext_vector_type(4)));

__device__ __forceinline__ uint16_t f2b(float f) {
  union { uint32_t u; float f; } v; v.f = f;
  uint32_t r = v.u + 0x7FFFu + ((v.u >> 16) & 1u);   // RNE
  return (uint16_t)(r >> 16);
}
__device__ __forceinline__ uint32_t pkbf(float lo, float hi) {
  __hip_bfloat162 h = __float22bfloat162_rn(float2{lo, hi});  // v_cvt_pk_bf16_f32
  union { __hip_bfloat162 h; uint32_t u; } c; c.h = h;
  return c.u;
}

// ---------------------------------------------------------------------------
// Pack W1/W2/W3 (fp32 [K][256] row-major) into bf16 MFMA-A-fragment order:
//   packed[((mt*KC + kc)*64 + lane)*8 + j] =
//       bf16( W[kc*32 + (lane>>4)*8 + j][mt*16 + (lane&15)] )
// mt = 16-col tile (0..15) — layout independent of encoder wave mapping.
// Also zero-inits msum (poisoned 0xAA by the harness).
// ---------------------------------------------------------------------------
__global__ __launch_bounds__(256) void pack_weights(
    const float* __restrict__ W1, const float* __restrict__ W2,
    const float* __restrict__ W3, uint16_t* __restrict__ pW,
    float* __restrict__ msum) {
  int p = blockIdx.x * blockDim.x + threadIdx.x;
  if (p < BATCH * NHID) msum[p] = 0.f;
  const float* W; int K; int base;
  if (p < 32768)      { W = W1; K = NIN;  base = 0; }
  else if (p < 98304) { W = W2; K = NHID; base = 32768; p -= 32768; }
  else                { W = W3; K = NHID; base = 98304; p -= 98304; }
  int j    = p & 7;
  int ln   = (p >> 3) & 63;
  int rest = p >> 9;
  int KC = K >> 5;
  int kc = rest % KC;
  int mt = rest / KC;
  int m = mt * 16 + (ln & 15);
  int k = kc * 32 + ((ln >> 4) << 3) + j;
  pW[base + (((mt * KC + kc) * 64 + ln) << 3) + j] = f2b(W[k * NHID + m]);
}

// ---------------------------------------------------------------------------
// Fused encoder. Block = 512 thr (8 waves), 128 tokens. Wave w owns hidden
// cols [32w, 32w+32) (mt = w*2+jt, jt in {0,1}); 8 token-tiles shared
// (B from LDS). acc[2][8] = 64 VGPRs (same budget as the 64-token version).
// ---------------------------------------------------------------------------
__global__ __launch_bounds__(512) void encoder(
    const float* __restrict__ x,        // [BATCH*NTOK][NIN] fp32
    const uint16_t* __restrict__ pW,
    const float* __restrict__ b1,
    const float* __restrict__ b2,
    const float* __restrict__ b3,
    float* __restrict__ msum) {         // [BATCH][NHID] fp32 accum
  __shared__ __align__(16) uint16_t Hs[MTILE * HPAD];  // 67584 B

  const int tid  = threadIdx.x;
  const int wave = tid >> 6;            // 0..7
  const int lane = tid & 63;
  const int l15  = lane & 15;
  const int q    = lane >> 4;
  const int tok0  = blockIdx.x * MTILE;
  const int batch = blockIdx.x / TPB;

  const uint16_t* pW1 = pW;             // KC=4
  const uint16_t* pW2 = pW + 32768;     // KC=8
  const uint16_t* pW3 = pW + 98304;     // KC=8

  // ---- stage x tile: fp32 -> bf16, 128 rows, stride XPAD ----
  {
    const int row = tid >> 2;           // 0..127
    const int c0  = (tid & 3) * 32;
    const float* xr = x + (size_t)(tok0 + row) * NIN + c0;
    for (int i = 0; i < 8; ++i) {
      float4 v = *(const float4*)(xr + i * 4);
      uint2 u = make_uint2(pkbf(v.x, v.y), pkbf(v.z, v.w));
      *(uint2*)&Hs[row * XPAD + c0 + i * 4] = u;
    }
  }
  __syncthreads();

  floatx4 acc[2][8];   // [jt][tt]

  // ---- layer 1: K = 128, A = W1^T, B = x ----
  for (int jt = 0; jt < 2; ++jt)
    for (int tt = 0; tt < 8; ++tt)
      acc[jt][tt] = (floatx4){0.f, 0.f, 0.f, 0.f};
#pragma unroll
  for (int kc = 0; kc < 4; ++kc) {
    bf16x8 a[2], b[8];
#pragma unroll
    for (int jt = 0; jt < 2; ++jt)
      a[jt] = *(const bf16x8*)(pW1 + ((((wave * 2 + jt) * 4 + kc) * 64 + lane) << 3));
#pragma unroll
    for (int tt = 0; tt < 8; ++tt)
      b[tt] = *(const bf16x8*)&Hs[(tt * 16 + l15) * XPAD + kc * 32 + q * 8];
#pragma unroll
    for (int jt = 0; jt < 2; ++jt)
#pragma unroll
      for (int tt = 0; tt < 8; ++tt)
        acc[jt][tt] = __builtin_amdgcn_mfma_f32_16x16x32_bf16(
            a[jt], b[tt], acc[jt][tt], 0, 0, 0);
  }
  __syncthreads();   // x reads done before h1 overwrites

#pragma unroll
  for (int jt = 0; jt < 2; ++jt) {
    const int jbase = wave * 32 + jt * 16 + q * 4;
    const float4 bb = *(const float4*)&b1[jbase];
#pragma unroll
    for (int tt = 0; tt < 8; ++tt) {
      const int t = tt * 16 + l15;
      float v0 = fmaxf(acc[jt][tt][0] + bb.x, 0.f);
      float v1 = fmaxf(acc[jt][tt][1] + bb.y, 0.f);
      float v2 = fmaxf(acc[jt][tt][2] + bb.z, 0.f);
      float v3 = fmaxf(acc[jt][tt][3] + bb.w, 0.f);
      *(uint2*)&Hs[t * HPAD + jbase] = make_uint2(pkbf(v0, v1), pkbf(v2, v3));
    }
  }
  __syncthreads();

  // ---- layer 2: K = 256, A = W2^T, B = h1 ----
  for (int jt = 0; jt < 2; ++jt)
    for (int tt = 0; tt < 8; ++tt)
      acc[jt][tt] = (floatx4){0.f, 0.f, 0.f, 0.f};
#pragma unroll
  for (int kc = 0; kc < 8; ++kc) {
    bf16x8 a[2], b[8];
#pragma unroll
    for (int jt = 0; jt < 2; ++jt)
      a[jt] = *(const bf16x8*)(pW2 + ((((wave * 2 + jt) * 8 + kc) * 64 + lane) << 3));
#pragma unroll
    for (int tt = 0; tt < 8; ++tt)
      b[tt] = *(const bf16x8*)&Hs[(tt * 16 + l15) * HPAD + kc * 32 + q * 8];
#pragma unroll
    for (int jt = 0; jt < 2; ++jt)
#pragma unroll
      for (int tt = 0; tt < 8; ++tt)
        acc[jt][tt] = __builtin_amdgcn_mfma_f32_16x16x32_bf16(
            a[jt], b[tt], acc[jt][tt], 0, 0, 0);
  }
  __syncthreads();   // h1 reads done before overwrite
#pragma unroll
  for (int jt = 0; jt < 2; ++jt) {
    const int jbase = wave * 32 + jt * 16 + q * 4;
    const float4 bb = *(const float4*)&b2[jbase];
#pragma unroll
    for (int tt = 0; tt < 8; ++tt) {
      const int t = tt * 16 + l15;
      float v0 = fmaxf(acc[jt][tt][0] + bb.x, 0.f);
      float v1 = fmaxf(acc[jt][tt][1] + bb.y, 0.f);
      float v2 = fmaxf(acc[jt][tt][2] + bb.z, 0.f);
      float v3 = fmaxf(acc[jt][tt][3] + bb.w, 0.f);
      *(uint2*)&Hs[t * HPAD + jbase] = make_uint2(pkbf(v0, v1), pkbf(v2, v3));
    }
  }
  __syncthreads();

  // ---- layer 3: K = 256, A = W3^T, B = h2, fused token-sum ----
  for (int jt = 0; jt < 2; ++jt)
    for (int tt = 0; tt < 8; ++tt)
      acc[jt][tt] = (floatx4){0.f, 0.f, 0.f, 0.f};
#pragma unroll
  for (int kc = 0; kc < 8; ++kc) {
    bf16x8 a[2], b[8];
#pragma unroll
    for (int jt = 0; jt < 2; ++jt)
      a[jt] = *(const bf16x8*)(pW3 + ((((wave * 2 + jt) * 8 + kc) * 64 + lane) << 3));
#pragma unroll
    for (int tt = 0; tt < 8; ++tt)
      b[tt] = *(const bf16x8*)&Hs[(tt * 16 + l15) * HPAD + kc * 32 + q * 8];
#pragma unroll
    for (int jt = 0; jt < 2; ++jt)
#pragma unroll
      for (int tt = 0; tt < 8; ++tt)
        acc[jt][tt] = __builtin_amdgcn_mfma_f32_16x16x32_bf16(
            a[jt], b[tt], acc[jt][tt], 0, 0, 0);
  }
  __syncthreads();   // h2 reads done before scratch overwrites Hs

  // bias + relu + partial token-sum over this lane's 8 t-tiles.
  // scratch row = (wave*2+jt)*4+q (0..63), 17-float4 stride: final-read
  // bank = (4c+4l+r)%32, 2-way max.
  {
    float4* scratch = (float4*)Hs;      // 64 rows x 17 float4 = 17408 B
#pragma unroll
    for (int jt = 0; jt < 2; ++jt) {
      const int jbase = wave * 32 + jt * 16 + q * 4;
      const float4 bb = *(const float4*)&b3[jbase];
      float s0 = 0.f, s1 = 0.f, s2 = 0.f, s3 = 0.f;
#pragma unroll
      for (int tt = 0; tt < 8; ++tt) {
        s0 += fmaxf(acc[jt][tt][0] + bb.x, 0.f);
        s1 += fmaxf(acc[jt][tt][1] + bb.y, 0.f);
        s2 += fmaxf(acc[jt][tt][2] + bb.z, 0.f);
        s3 += fmaxf(acc[jt][tt][3] + bb.w, 0.f);
      }
      scratch[((wave * 2 + jt) * 4 + q) * 17 + l15] = (float4){s0, s1, s2, s3};
    }
  }
  __syncthreads();
  if (tid < 256) {
    const int c = tid >> 2;             // scratch row 0..63
    const int r = tid & 3;
    const float* sf = (const float*)Hs;
    float v = 0.f;
#pragma unroll
    for (int l = 0; l < 16; ++l)
      v += sf[c * 68 + l * 4 + r];      // padded stride: 17 float4 = 68 f
    // row c = (wave*2+jt)*4+q  ->  j = (c>>2)*16 + (c&3)*4 + r
    const int j = ((c >> 2) << 4) + ((c & 3) << 2) + r;
    atomicAdd(&msum[batch * NHID + j], v);
  }
}

// ---------------------------------------------------------------------------
// Decoder: one block per batch, 1024 threads; 4-wide j-vectorization +
// 8-way K-split (R12).
// ---------------------------------------------------------------------------
__global__ __launch_bounds__(1024) void decoder(
    const float* __restrict__ msum,
    const float* __restrict__ D1, const float* __restrict__ c1,
    const float* __restrict__ D2, const float* __restrict__ c2,
    const float* __restrict__ D3, const float* __restrict__ c3,
    float* __restrict__ out) {
  __shared__ float p[NHID];
  __shared__ float d1[NDEC];
  __shared__ float d2[NDEC];
  __shared__ __align__(16) float red[4096];   // 16 KB
  const int b = blockIdx.x, t = threadIdx.x;

  if (t < NHID) {
    float m = msum[b * NHID + t] * (1.f / NTOK);
    p[t] = m * m;                        // relu(m^2) == m^2
  }
  __syncthreads();

  const int jg = t & 127;                // j-group of 4
  const int ks = t >> 7;                 // 0..7 K-split

  // ---- layer 1: K = 256 -> 32 k per split ----
  {
    const float4* D1v = (const float4*)D1;   // [256][128] float4
    float4 s = {0.f, 0.f, 0.f, 0.f};
    for (int k = ks * 32; k < ks * 32 + 32; ++k) {
      float4 w = D1v[k * 128 + jg];
      float pv = p[k];
      s.x += pv * w.x; s.y += pv * w.y; s.z += pv * w.z; s.w += pv * w.w;
    }
    *(float4*)&red[t * 4] = s;
    __syncthreads();
    if (t < NDEC) {
      float v = c1[t];
#pragma unroll
      for (int i = 0; i < 8; ++i) v += red[i * 512 + t];
      d1[t] = fmaxf(v, 0.f);
    }
    __syncthreads();
  }

  // ---- layer 2: K = 512 -> 64 k per split ----
  {
    const float4* D2v = (const float4*)D2;   // [512][128] float4
    float4 s = {0.f, 0.f, 0.f, 0.f};
    for (int k = ks * 64; k < ks * 64 + 64; ++k) {
      float4 w = D2v[k * 128 + jg];
      float hv = d1[k];
      s.x += hv * w.x; s.y += hv * w.y; s.z += hv * w.z; s.w += hv * w.w;
    }
    *(float4*)&red[t * 4] = s;
    __syncthreads();
    if (t < NDEC) {
      float v = c2[t];
#pragma unroll
      for (int i = 0; i < 8; ++i) v += red[i * 512 + t];
      d2[t] = fmaxf(v, 0.f);
    }
    __syncthreads();
  }

  // ---- layer 3: [512][10]; 64 k-chunks x 16 j-slots (10 valid) ----
  {
    const int j3 = t & 15;
    const int kc = t >> 4;               // 0..63, 8 k's each
    float s = 0.f;
    if (j3 < NOUTC)
      for (int k = kc * 8; k < kc * 8 + 8; ++k)
        s += d2[k] * D3[k * NOUTC + j3];
    red[t] = s;
    __syncthreads();
    if (t < NOUTC) {
      float v = c3[t];
#pragma unroll
      for (int i = 0; i < 64; ++i) v += red[i * 16 + t];
      out[b * NOUTC + t] = v;
    }
  }
}

// ---------------------------------------------------------------------------
extern "C" void kernel_launch(void* const* d_in, const int* in_sizes, int n_in,
                              void* d_out, int out_size, void* d_ws, size_t ws_size,
                              hipStream_t stream) {
  const float* x  = (const float*)d_in[0];
  const float* W1 = (const float*)d_in[1];
  const float* b1 = (const float*)d_in[2];
  const float* W2 = (const float*)d_in[3];
  const float* b2 = (const float*)d_in[4];
  const float* W3 = (const float*)d_in[5];
  const float* b3 = (const float*)d_in[6];
  const float* D1 = (const float*)d_in[7];
  const float* c1 = (const float*)d_in[8];
  const float* D2 = (const float*)d_in[9];
  const float* c2 = (const float*)d_in[10];
  const float* D3 = (const float*)d_in[11];
  const float* c3 = (const float*)d_in[12];

  // ws: [0,320K) packed bf16 W | [384K,416K) msum
  uint16_t* pW   = (uint16_t*)d_ws;
  float*    msum = (float*)((char*)d_ws + 384 * 1024);

  pack_weights<<<640, 256, 0, stream>>>(W1, W2, W3, pW, msum);
  encoder<<<NBLK, 512, 0, stream>>>(x, pW, b1, b2, b3, msum);
  decoder<<<BATCH, 1024, 0, stream>>>(msum, D1, c1, D2, c2, D3, c3,
                                      (float*)d_out);
}

// Round 18
// 173.231 us; speedup vs baseline: 1.0284x; 1.0284x over previous
//
#include <hip/hip_runtime.h>
#include <hip/hip_bf16.h>
#include <stdint.h>

// ---------------------------------------------------------------------------
// TensorNet: fused encoder MLP (128->256->256->256, relu) over 32x4096 tokens,
// per-batch mean -> p = relu(m^2) -> decoder MLP (256->512->512->10).
// Inputs/outputs fp32. Encoder via bf16 MFMA (A=weights M=hidden, B=act
// N=tokens) + fp32 accum. FINAL = R12/R16 configuration (best measured:
// 172.7us, reproduced).
//
// Ceiling arithmetic: MFMA floor ~17us, L2 weight traffic ~19us, LDS ~10us;
// measured encoder ~65us = 3x max component = 7-barrier phase serialization.
// Every lever against it regressed with counter evidence:
//  - __launch_bounds__(256,4): VGPR=64 < acc live-set -> scratch spills
//    (+20MB HBM writes, R5).
//  - direct-global layer-1 B + shfl butterfly: 4x-redundant x reads (R5/6).
//  - manual a-frag ping-pong: compiler already optimal, +VALU (R13).
//  - MTILE=128: blocks/CU 4->2 (less barrier-drain overlap) + 1.7x LDS
//    conflicts (R17).
//  - cooperative single-kernel: VGPR 92->176 AND fails graph capture (R11).
//  - decoder-tail fusion into encoder: dispatch 67->140us w/ or w/o fence,
//    occupancy -40% (R14/15).
//  - barrier-free 16-token waves (paper design): 4x weight reads = 2.6GB L2
//    ~ 75us. Dead on arithmetic.
// Remaining ~60us = 3 launch nodes x ~20us at the dependency floor
// (pack -> encoder -> decoder; dispatch-order tricks forbidden by G16).
// ---------------------------------------------------------------------------

#define NIN   128
#define NHID  256
#define NDEC  512
#define NOUTC 10
#define BATCH 32
#define NTOK  4096
#define MTILE 64
#define NBLK  (BATCH * (NTOK / MTILE))   // 2048 encoder tiles
#define XPAD  136                         // x-tile LDS row stride (bf16)
#define HPAD  264                         // h-tile LDS row stride (bf16)

typedef short bf16x8 __attribute__((ext_vector_type(8)));
typedef float floatx4 __attribute__((ext_vector_type(4)));

__device__ __forceinline__ uint16_t f2b(float f) {
  union { uint32_t u; float f; } v; v.f = f;
  uint32_t r = v.u + 0x7FFFu + ((v.u >> 16) & 1u);   // RNE
  return (uint16_t)(r >> 16);
}
__device__ __forceinline__ uint32_t pkbf(float lo, float hi) {
  __hip_bfloat162 h = __float22bfloat162_rn(float2{lo, hi});  // v_cvt_pk_bf16_f32
  union { __hip_bfloat162 h; uint32_t u; } c; c.h = h;
  return c.u;
}

// ---------------------------------------------------------------------------
// Pack W1/W2/W3 (fp32 [K][256] row-major) into bf16 MFMA-A-fragment order.
// Also zero-inits msum (poisoned 0xAA by the harness).
// ---------------------------------------------------------------------------
__global__ __launch_bounds__(256) void pack_weights(
    const float* __restrict__ W1, const float* __restrict__ W2,
    const float* __restrict__ W3, uint16_t* __restrict__ pW,
    float* __restrict__ msum) {
  int p = blockIdx.x * blockDim.x + threadIdx.x;
  if (p < BATCH * NHID) msum[p] = 0.f;
  const float* W; int K; int base;
  if (p < 32768)      { W = W1; K = NIN;  base = 0; }
  else if (p < 98304) { W = W2; K = NHID; base = 32768; p -= 32768; }
  else                { W = W3; K = NHID; base = 98304; p -= 98304; }
  int j    = p & 7;
  int ln   = (p >> 3) & 63;
  int rest = p >> 9;
  int KC = K >> 5;
  int kc = rest % KC;
  int mt = rest / KC;
  int m = mt * 16 + (ln & 15);
  int k = kc * 32 + ((ln >> 4) << 3) + j;
  pW[base + (((mt * KC + kc) * 64 + ln) << 3) + j] = f2b(W[k * NHID + m]);
}

// ---------------------------------------------------------------------------
// Fused encoder. Block = 256 thr (4 waves), 64 tokens. Wave w owns hidden
// rows [64w,64w+64) (A = packed weights); token tiles shared (B from LDS).
// NOTE: plain __launch_bounds__(256) — (256,4) forces VGPR=64 and spills
// the 64-VGPR accumulator (R5: +20MB HBM writes).
// ---------------------------------------------------------------------------
__global__ __launch_bounds__(256) void encoder(
    const float* __restrict__ x,        // [BATCH*NTOK][NIN] fp32
    const uint16_t* __restrict__ pW,
    const float* __restrict__ b1,
    const float* __restrict__ b2,
    const float* __restrict__ b3,
    float* __restrict__ msum) {         // [BATCH][NHID] fp32 accum
  __shared__ __align__(16) uint16_t Hs[MTILE * HPAD];  // 33792 B

  const int tid  = threadIdx.x;
  const int wave = tid >> 6;
  const int lane = tid & 63;
  const int l15  = lane & 15;
  const int q    = lane >> 4;
  const int tok0  = blockIdx.x * MTILE;
  const int batch = blockIdx.x >> 6;

  const uint16_t* pW1 = pW;             // KC=4
  const uint16_t* pW2 = pW + 32768;     // KC=8
  const uint16_t* pW3 = pW + 98304;     // KC=8

  // ---- stage x tile: fp32 -> bf16, rows stride XPAD ----
  {
    const int row = tid >> 2;
    const int c0  = (tid & 3) * 32;
    const float* xr = x + (size_t)(tok0 + row) * NIN + c0;
    for (int i = 0; i < 8; ++i) {
      float4 v = *(const float4*)(xr + i * 4);
      uint2 u = make_uint2(pkbf(v.x, v.y), pkbf(v.z, v.w));
      *(uint2*)&Hs[row * XPAD + c0 + i * 4] = u;
    }
  }
  __syncthreads();

  floatx4 acc[4][4];   // [jt][tt]

  // ---- layer 1: K = 128, A = W1^T, B = x ----
  for (int jt = 0; jt < 4; ++jt)
    for (int tt = 0; tt < 4; ++tt)
      acc[jt][tt] = (floatx4){0.f, 0.f, 0.f, 0.f};
#pragma unroll
  for (int kc = 0; kc < 4; ++kc) {
    bf16x8 a[4], b[4];
#pragma unroll
    for (int jt = 0; jt < 4; ++jt)
      a[jt] = *(const bf16x8*)(pW1 + ((((wave * 4 + jt) * 4 + kc) * 64 + lane) << 3));
#pragma unroll
    for (int tt = 0; tt < 4; ++tt)
      b[tt] = *(const bf16x8*)&Hs[(tt * 16 + l15) * XPAD + kc * 32 + q * 8];
#pragma unroll
    for (int jt = 0; jt < 4; ++jt)
#pragma unroll
      for (int tt = 0; tt < 4; ++tt)
        acc[jt][tt] = __builtin_amdgcn_mfma_f32_16x16x32_bf16(
            a[jt], b[tt], acc[jt][tt], 0, 0, 0);
  }
  __syncthreads();   // x reads done before h1 overwrites

#pragma unroll
  for (int jt = 0; jt < 4; ++jt) {
    const int jbase = wave * 64 + jt * 16 + q * 4;
    const float4 bb = *(const float4*)&b1[jbase];
#pragma unroll
    for (int tt = 0; tt < 4; ++tt) {
      const int t = tt * 16 + l15;
      float v0 = fmaxf(acc[jt][tt][0] + bb.x, 0.f);
      float v1 = fmaxf(acc[jt][tt][1] + bb.y, 0.f);
      float v2 = fmaxf(acc[jt][tt][2] + bb.z, 0.f);
      float v3 = fmaxf(acc[jt][tt][3] + bb.w, 0.f);
      *(uint2*)&Hs[t * HPAD + jbase] = make_uint2(pkbf(v0, v1), pkbf(v2, v3));
    }
  }
  __syncthreads();

  // ---- layer 2: K = 256, A = W2^T, B = h1 ----
  for (int jt = 0; jt < 4; ++jt)
    for (int tt = 0; tt < 4; ++tt)
      acc[jt][tt] = (floatx4){0.f, 0.f, 0.f, 0.f};
#pragma unroll
  for (int kc = 0; kc < 8; ++kc) {
    bf16x8 a[4], b[4];
#pragma unroll
    for (int jt = 0; jt < 4; ++jt)
      a[jt] = *(const bf16x8*)(pW2 + ((((wave * 4 + jt) * 8 + kc) * 64 + lane) << 3));
#pragma unroll
    for (int tt = 0; tt < 4; ++tt)
      b[tt] = *(const bf16x8*)&Hs[(tt * 16 + l15) * HPAD + kc * 32 + q * 8];
#pragma unroll
    for (int jt = 0; jt < 4; ++jt)
#pragma unroll
      for (int tt = 0; tt < 4; ++tt)
        acc[jt][tt] = __builtin_amdgcn_mfma_f32_16x16x32_bf16(
            a[jt], b[tt], acc[jt][tt], 0, 0, 0);
  }
  __syncthreads();   // h1 reads done before overwrite
#pragma unroll
  for (int jt = 0; jt < 4; ++jt) {
    const int jbase = wave * 64 + jt * 16 + q * 4;
    const float4 bb = *(const float4*)&b2[jbase];
#pragma unroll
    for (int tt = 0; tt < 4; ++tt) {
      const int t = tt * 16 + l15;
      float v0 = fmaxf(acc[jt][tt][0] + bb.x, 0.f);
      float v1 = fmaxf(acc[jt][tt][1] + bb.y, 0.f);
      float v2 = fmaxf(acc[jt][tt][2] + bb.z, 0.f);
      float v3 = fmaxf(acc[jt][tt][3] + bb.w, 0.f);
      *(uint2*)&Hs[t * HPAD + jbase] = make_uint2(pkbf(v0, v1), pkbf(v2, v3));
    }
  }
  __syncthreads();

  // ---- layer 3: K = 256, A = W3^T, B = h2, fused token-sum ----
  for (int jt = 0; jt < 4; ++jt)
    for (int tt = 0; tt < 4; ++tt)
      acc[jt][tt] = (floatx4){0.f, 0.f, 0.f, 0.f};
#pragma unroll
  for (int kc = 0; kc < 8; ++kc) {
    bf16x8 a[4], b[4];
#pragma unroll
    for (int jt = 0; jt < 4; ++jt)
      a[jt] = *(const bf16x8*)(pW3 + ((((wave * 4 + jt) * 8 + kc) * 64 + lane) << 3));
#pragma unroll
    for (int tt = 0; tt < 4; ++tt)
      b[tt] = *(const bf16x8*)&Hs[(tt * 16 + l15) * HPAD + kc * 32 + q * 8];
#pragma unroll
    for (int jt = 0; jt < 4; ++jt)
#pragma unroll
      for (int tt = 0; tt < 4; ++tt)
        acc[jt][tt] = __builtin_amdgcn_mfma_f32_16x16x32_bf16(
            a[jt], b[tt], acc[jt][tt], 0, 0, 0);
  }
  __syncthreads();   // h2 reads done before scratch overwrites Hs

  // bias + relu + partial token-sum; scratch rows padded 17 float4 so the
  // final read's bank = (4c+4l+r)%32 (2-way, free) not (4l+r)%32 (16-way).
  {
    float4* scratch = (float4*)Hs;
#pragma unroll
    for (int jt = 0; jt < 4; ++jt) {
      const int jbase = wave * 64 + jt * 16 + q * 4;
      const float4 bb = *(const float4*)&b3[jbase];
      float s0 = 0.f, s1 = 0.f, s2 = 0.f, s3 = 0.f;
#pragma unroll
      for (int tt = 0; tt < 4; ++tt) {
        s0 += fmaxf(acc[jt][tt][0] + bb.x, 0.f);
        s1 += fmaxf(acc[jt][tt][1] + bb.y, 0.f);
        s2 += fmaxf(acc[jt][tt][2] + bb.z, 0.f);
        s3 += fmaxf(acc[jt][tt][3] + bb.w, 0.f);
      }
      scratch[((wave * 4 + jt) * 4 + q) * 17 + l15] = (float4){s0, s1, s2, s3};
    }
  }
  __syncthreads();
  {
    const int c = tid >> 2;
    const int r = tid & 3;
    const float* sf = (const float*)Hs;
    float v = 0.f;
#pragma unroll
    for (int l = 0; l < 16; ++l)
      v += sf[c * 68 + l * 4 + r];
    const int wv = c >> 4, jt = (c >> 2) & 3, qq = c & 3;
    const int j = wv * 64 + jt * 16 + qq * 4 + r;
    atomicAdd(&msum[batch * NHID + j], v);
  }
}

// ---------------------------------------------------------------------------
// Decoder: one block per batch, 1024 threads; 4-wide j-vectorization +
// 8-way K-split (R12).
// ---------------------------------------------------------------------------
__global__ __launch_bounds__(1024) void decoder(
    const float* __restrict__ msum,
    const float* __restrict__ D1, const float* __restrict__ c1,
    const float* __restrict__ D2, const float* __restrict__ c2,
    const float* __restrict__ D3, const float* __restrict__ c3,
    float* __restrict__ out) {
  __shared__ float p[NHID];
  __shared__ float d1[NDEC];
  __shared__ float d2[NDEC];
  __shared__ __align__(16) float red[4096];   // 16 KB
  const int b = blockIdx.x, t = threadIdx.x;

  if (t < NHID) {
    float m = msum[b * NHID + t] * (1.f / NTOK);
    p[t] = m * m;                        // relu(m^2) == m^2
  }
  __syncthreads();

  const int jg = t & 127;                // j-group of 4
  const int ks = t >> 7;                 // 0..7 K-split

  // ---- layer 1: K = 256 -> 32 k per split ----
  {
    const float4* D1v = (const float4*)D1;   // [256][128] float4
    float4 s = {0.f, 0.f, 0.f, 0.f};
    for (int k = ks * 32; k < ks * 32 + 32; ++k) {
      float4 w = D1v[k * 128 + jg];
      float pv = p[k];
      s.x += pv * w.x; s.y += pv * w.y; s.z += pv * w.z; s.w += pv * w.w;
    }
    *(float4*)&red[t * 4] = s;
    __syncthreads();
    if (t < NDEC) {
      float v = c1[t];
#pragma unroll
      for (int i = 0; i < 8; ++i) v += red[i * 512 + t];
      d1[t] = fmaxf(v, 0.f);
    }
    __syncthreads();
  }

  // ---- layer 2: K = 512 -> 64 k per split ----
  {
    const float4* D2v = (const float4*)D2;   // [512][128] float4
    float4 s = {0.f, 0.f, 0.f, 0.f};
    for (int k = ks * 64; k < ks * 64 + 64; ++k) {
      float4 w = D2v[k * 128 + jg];
      float hv = d1[k];
      s.x += hv * w.x; s.y += hv * w.y; s.z += hv * w.z; s.w += hv * w.w;
    }
    *(float4*)&red[t * 4] = s;
    __syncthreads();
    if (t < NDEC) {
      float v = c2[t];
#pragma unroll
      for (int i = 0; i < 8; ++i) v += red[i * 512 + t];
      d2[t] = fmaxf(v, 0.f);
    }
    __syncthreads();
  }

  // ---- layer 3: [512][10]; 64 k-chunks x 16 j-slots (10 valid) ----
  {
    const int j3 = t & 15;
    const int kc = t >> 4;               // 0..63, 8 k's each
    float s = 0.f;
    if (j3 < NOUTC)
      for (int k = kc * 8; k < kc * 8 + 8; ++k)
        s += d2[k] * D3[k * NOUTC + j3];
    red[t] = s;
    __syncthreads();
    if (t < NOUTC) {
      float v = c3[t];
#pragma unroll
      for (int i = 0; i < 64; ++i) v += red[i * 16 + t];
      out[b * NOUTC + t] = v;
    }
  }
}

// ---------------------------------------------------------------------------
extern "C" void kernel_launch(void* const* d_in, const int* in_sizes, int n_in,
                              void* d_out, int out_size, void* d_ws, size_t ws_size,
                              hipStream_t stream) {
  const float* x  = (const float*)d_in[0];
  const float* W1 = (const float*)d_in[1];
  const float* b1 = (const float*)d_in[2];
  const float* W2 = (const float*)d_in[3];
  const float* b2 = (const float*)d_in[4];
  const float* W3 = (const float*)d_in[5];
  const float* b3 = (const float*)d_in[6];
  const float* D1 = (const float*)d_in[7];
  const float* c1 = (const float*)d_in[8];
  const float* D2 = (const float*)d_in[9];
  const float* c2 = (const float*)d_in[10];
  const float* D3 = (const float*)d_in[11];
  const float* c3 = (const float*)d_in[12];

  // ws: [0,320K) packed bf16 W | [384K,416K) msum
  uint16_t* pW   = (uint16_t*)d_ws;
  float*    msum = (float*)((char*)d_ws + 384 * 1024);

  pack_weights<<<640, 256, 0, stream>>>(W1, W2, W3, pW, msum);
  encoder<<<NBLK, 256, 0, stream>>>(x, pW, b1, b2, b3, msum);
  decoder<<<BATCH, 1024, 0, stream>>>(msum, D1, c1, D2, c2, D3, c3,
                                      (float*)d_out);
}